// Round 1
// baseline (438.055 us; speedup 1.0000x reference)
//
#include <hip/hip_runtime.h>
#include <hip/hip_bf16.h>
#include <stdint.h>

// Problem dims (fixed by reference setup_inputs)
#define B_SZ 128
#define R_SZ 36
#define W_SZ 60
#define D_SZ 1024
#define MARGIN 0.2f

typedef __attribute__((ext_vector_type(8))) short short8;   // 8 bf16 = 4 VGPRs (MFMA A/B frag)
typedef __attribute__((ext_vector_type(4))) float f32x4;    // MFMA C/D frag

__device__ __forceinline__ unsigned short f2bf(float f) {
    union { float f; uint32_t u; } x; x.f = f;
    uint32_t u = x.u;
    // round-to-nearest-even bf16
    uint32_t r = (u + 0x7FFFu + ((u >> 16) & 1u)) >> 16;
    return (unsigned short)r;
}

// fp32 -> bf16 conversion, 4 elems/thread
__global__ __launch_bounds__(256) void convert_bf16_kernel(
        const float* __restrict__ src, unsigned short* __restrict__ dst, int n4) {
    int i = blockIdx.x * blockDim.x + threadIdx.x;
    if (i < n4) {
        float4 v = reinterpret_cast<const float4*>(src)[i];
        ushort4 o;
        o.x = f2bf(v.x); o.y = f2bf(v.y); o.z = f2bf(v.z); o.w = f2bf(v.w);
        reinterpret_cast<ushort4*>(dst)[i] = o;
    }
}

// One wave computes one (caption i, image j) pair:
//  - 48x64 MFMA tile (3 row-frags x 4 col-frags of 16x16x32 bf16), K = 1024 (32 steps)
//  - epilogue: max over regions (rows), masked mean over words (cols) -> S[j*128 + i]
// Row clamping: A rows 36..47 duplicate row 35 (max unchanged).
// Col clamping: B cols 60..63 duplicate col 59 (always masked by s_l <= 60).
__global__ __launch_bounds__(256) void scores_kernel(
        const unsigned short* __restrict__ imb,   // [128][36][1024] bf16
        const unsigned short* __restrict__ sb,    // [128][60][1024] bf16
        const int* __restrict__ s_l,
        float* __restrict__ S)                    // [j][i]
{
    const int wid  = threadIdx.x >> 6;   // 0..3
    const int lane = threadIdx.x & 63;
    const int l15  = lane & 15;
    const int kgrp = lane >> 4;          // 0..3

    // XCD-chunked swizzle: XCD k gets a contiguous stripe of the (jt,it) grid
    int bid = blockIdx.x;                // 0..4095
    int swz = (bid & 7) * 512 + (bid >> 3);
    int jt = swz >> 6;                   // 0..63
    int it = swz & 63;                   // 0..63
    int j = jt * 2 + (wid >> 1);
    int i = it * 2 + (wid & 1);

    // Per-lane fragment row base pointers (bf16 elements)
    const unsigned short* arow[3];
#pragma unroll
    for (int rf = 0; rf < 3; ++rf) {
        int r = rf * 16 + l15; if (r > R_SZ - 1) r = R_SZ - 1;
        arow[rf] = imb + ((size_t)j * R_SZ + r) * D_SZ + kgrp * 8;
    }
    const unsigned short* brow[4];
#pragma unroll
    for (int cf = 0; cf < 4; ++cf) {
        int w = cf * 16 + l15; if (w > W_SZ - 1) w = W_SZ - 1;
        brow[cf] = sb + ((size_t)i * W_SZ + w) * D_SZ + kgrp * 8;
    }

    f32x4 acc[3][4] = {};

    for (int kk = 0; kk < 32; ++kk) {
        const int ko = kk * 32;          // bf16 elems along D
        short8 a[3], b[4];
#pragma unroll
        for (int rf = 0; rf < 3; ++rf)
            a[rf] = *reinterpret_cast<const short8*>(arow[rf] + ko);
#pragma unroll
        for (int cf = 0; cf < 4; ++cf)
            b[cf] = *reinterpret_cast<const short8*>(brow[cf] + ko);
#pragma unroll
        for (int rf = 0; rf < 3; ++rf)
#pragma unroll
            for (int cf = 0; cf < 4; ++cf)
                acc[rf][cf] = __builtin_amdgcn_mfma_f32_16x16x32_bf16(
                    a[rf], b[cf], acc[rf][cf], 0, 0, 0);
    }

    // Epilogue: per-column max over all 48 tile rows (rows >=36 are dups of row 35)
    const int nw = s_l[i];
    float sum = 0.0f;
#pragma unroll
    for (int cf = 0; cf < 4; ++cf) {
        float m = acc[0][cf][0];
#pragma unroll
        for (int rf = 0; rf < 3; ++rf)
#pragma unroll
            for (int e = 0; e < 4; ++e)
                m = fmaxf(m, acc[rf][cf][e]);
        // combine the 4 row-subsets held by lane groups (lane>>4)
        m = fmaxf(m, __shfl_xor(m, 16));
        m = fmaxf(m, __shfl_xor(m, 32));
        int w = cf * 16 + l15;
        if (w < nw) sum += m;
    }
    // sum over the 16 distinct columns within each lane group (groups are duplicates)
    sum += __shfl_xor(sum, 1);
    sum += __shfl_xor(sum, 2);
    sum += __shfl_xor(sum, 4);
    sum += __shfl_xor(sum, 8);

    if (lane == 0) S[j * B_SZ + i] = sum / (float)nw;
}

// Contrastive loss over the 128x128 score matrix, single block
__global__ __launch_bounds__(256) void loss_kernel(
        const float* __restrict__ S, float* __restrict__ out) {
    __shared__ float diag[B_SZ];
    __shared__ float red[256];
    int t = threadIdx.x;
    if (t < B_SZ) diag[t] = S[t * (B_SZ + 1)];
    __syncthreads();
    float acc = 0.0f;
    for (int idx = t; idx < B_SZ * B_SZ; idx += 256) {
        int a = idx >> 7, b = idx & (B_SZ - 1);
        if (a != b) {
            float v = S[idx];
            acc += fmaxf(MARGIN + v - diag[a], 0.0f)
                 + fmaxf(MARGIN + v - diag[b], 0.0f);
        }
    }
    red[t] = acc;
    __syncthreads();
    for (int s = 128; s > 0; s >>= 1) {
        if (t < s) red[t] += red[t + s];
        __syncthreads();
    }
    if (t == 0) out[0] = red[0];
}

extern "C" void kernel_launch(void* const* d_in, const int* in_sizes, int n_in,
                              void* d_out, int out_size, void* d_ws, size_t ws_size,
                              hipStream_t stream) {
    const float* im  = (const float*)d_in[0];
    const float* s   = (const float*)d_in[1];
    const int*   s_l = (const int*)d_in[2];
    // d_in[3] (x) is unused by the math

    const int n_im = B_SZ * R_SZ * D_SZ;   // 4,718,592
    const int n_s  = B_SZ * W_SZ * D_SZ;   // 7,864,320

    unsigned short* imb = (unsigned short*)d_ws;
    unsigned short* sb  = imb + n_im;
    float* S = (float*)(sb + n_s);         // 128*128 floats

    convert_bf16_kernel<<<(n_im / 4 + 255) / 256, 256, 0, stream>>>(im, imb, n_im / 4);
    convert_bf16_kernel<<<(n_s  / 4 + 255) / 256, 256, 0, stream>>>(s,  sb,  n_s  / 4);

    scores_kernel<<<4096, 256, 0, stream>>>(imb, sb, s_l, S);

    loss_kernel<<<1, 256, 0, stream>>>(S, (float*)d_out);
}

// Round 2
// 163.086 us; speedup vs baseline: 2.6860x; 2.6860x over previous
//
#include <hip/hip_runtime.h>
#include <hip/hip_bf16.h>
#include <stdint.h>

// Problem dims (fixed by reference setup_inputs)
#define B_SZ 128
#define R_SZ 36       // real regions per image
#define RP_SZ 48      // padded regions (dup row 35) -> multiple of 16
#define W_SZ 60       // real words per caption
#define WP_SZ 64      // padded words (dup word 59, masked in epilogue)
#define D_SZ 1024
#define MARGIN 0.2f

typedef __attribute__((ext_vector_type(8))) short short8;   // 8 bf16 (MFMA A/B frag)
typedef __attribute__((ext_vector_type(4))) float f32x4;    // MFMA C/D frag

typedef __attribute__((address_space(3))) unsigned int lds_u32;
typedef const __attribute__((address_space(1))) unsigned int glb_u32;

__device__ __forceinline__ void gload16(const unsigned short* g, unsigned short* l) {
    __builtin_amdgcn_global_load_lds((glb_u32*)g, (lds_u32*)l, 16, 0, 0);
}

__device__ __forceinline__ unsigned short f2bf(float f) {
    union { float f; uint32_t u; } x; x.f = f;
    uint32_t u = x.u;
    uint32_t r = (u + 0x7FFFu + ((u >> 16) & 1u)) >> 16;   // RNE bf16
    return (unsigned short)r;
}

// fp32 -> bf16 with row padding: dst [B][rows_dst][1024], src [B][rows_src][1024]
// rows >= rows_src duplicate row rows_src-1 (safe for max; masked for words).
__global__ __launch_bounds__(256) void convert_pad_kernel(
        const float* __restrict__ src, unsigned short* __restrict__ dst,
        int rows_dst, int rows_src, int n4) {
    int i = blockIdx.x * 256 + threadIdx.x;
    if (i >= n4) return;
    int idx = i * 4;
    int d  = idx & (D_SZ - 1);
    int rj = idx >> 10;              // j*rows_dst + r
    int r  = rj % rows_dst;
    int j  = rj / rows_dst;
    int rs = r < rows_src ? r : rows_src - 1;
    const float4 v = *reinterpret_cast<const float4*>(src + (((size_t)j * rows_src + rs) << 10) + d);
    ushort4 o;
    o.x = f2bf(v.x); o.y = f2bf(v.y); o.z = f2bf(v.z); o.w = f2bf(v.w);
    reinterpret_cast<ushort4*>(dst)[i] = o;
}

// Fused GEMM + MISA epilogue.
// Block tile: BM=192 (4 images x 48 padded regions) x BN=256 (4 captions x 64 padded words), BK=64.
// 8 waves (2Mx4N), per-wave 96x64 (acc[6][4] of 16x16x32 bf16 frags).
// LDS: As[192][64] + Bs[256][64] bf16 (56 KB), XOR slot-swizzle (slot ^= row&7):
//   linear global_load_lds dest + inverse-swizzled global source + swizzled ds_read.
__global__ __launch_bounds__(512, 2) void scores_kernel(
        const unsigned short* __restrict__ imb,   // [128][48][1024] bf16 (padded)
        const unsigned short* __restrict__ sb,    // [128][64][1024] bf16 (padded)
        const int* __restrict__ s_l,
        float* __restrict__ S)                    // [j][i]
{
    __shared__ unsigned short As[192 * 64];
    __shared__ unsigned short Bs[256 * 64];

    const int tid  = threadIdx.x;
    const int wid  = tid >> 6;        // 0..7
    const int lane = tid & 63;
    const int l15  = lane & 15;
    const int kgrp = lane >> 4;       // 0..3
    const int wr   = wid >> 2;        // 0..1 (M)
    const int wc   = wid & 3;         // 0..3 (N)

    // XCD-chunked swizzle over 1024 blocks (it-major chunks: B-panel stays in XCD L2)
    int bid = blockIdx.x;
    int swz = (bid & 7) * 128 + (bid >> 3);
    int jt = swz & 31;                // 0..31 (4 images each)
    int it = swz >> 5;                // 0..31 (4 captions each)

    // staging lane decomposition: 8 lanes per 128B row-segment, inverse-swizzled source slot
    const int lrow = lane >> 3;                   // 0..7
    const int slot = (lane & 7) ^ lrow;           // source slot so LDS[row][s] = G[row][s^(row&7)]

    // per-lane global row bases (constant over kt)
    const unsigned short* gA[3];
    unsigned short* lA[3];
#pragma unroll
    for (int c = 0; c < 3; ++c) {
        int chunk = wid + c * 8;                  // 0..23
        int row = chunk * 8 + lrow;               // 0..191
        gA[c] = imb + (size_t)(jt * 192 + row) * D_SZ + slot * 8;
        lA[c] = As + chunk * 512;                 // 1024 B per chunk
    }
    const unsigned short* gB[4];
    unsigned short* lB[4];
#pragma unroll
    for (int c = 0; c < 4; ++c) {
        int chunk = wid + c * 8;                  // 0..31
        int row = chunk * 8 + lrow;               // 0..255
        gB[c] = sb + (size_t)(it * 256 + row) * D_SZ + slot * 8;
        lB[c] = Bs + chunk * 512;
    }

    f32x4 acc[6][4] = {};

    for (int kt = 0; kt < 16; ++kt) {
        const int ko = kt * 64;
#pragma unroll
        for (int c = 0; c < 3; ++c) gload16(gA[c] + ko, lA[c]);
#pragma unroll
        for (int c = 0; c < 4; ++c) gload16(gB[c] + ko, lB[c]);

        __syncthreads();   // drains vmcnt: staged tile visible

#pragma unroll
        for (int kk2 = 0; kk2 < 2; ++kk2) {
            short8 a[6], b[4];
#pragma unroll
            for (int rf = 0; rf < 6; ++rf) {
                int row = wr * 96 + rf * 16 + l15;
                int sl = (kk2 * 4 + kgrp) ^ (l15 & 7);
                a[rf] = *reinterpret_cast<const short8*>(As + row * 64 + sl * 8);
            }
#pragma unroll
            for (int cf = 0; cf < 4; ++cf) {
                int row = wc * 64 + cf * 16 + l15;
                int sl = (kk2 * 4 + kgrp) ^ (l15 & 7);
                b[cf] = *reinterpret_cast<const short8*>(Bs + row * 64 + sl * 8);
            }
#pragma unroll
            for (int rf = 0; rf < 6; ++rf)
#pragma unroll
                for (int cf = 0; cf < 4; ++cf)
                    acc[rf][cf] = __builtin_amdgcn_mfma_f32_16x16x32_bf16(
                        a[rf], b[cf], acc[rf][cf], 0, 0, 0);
        }
        __syncthreads();   // tile consumed; safe to overwrite next kt
    }

    // Epilogue: wave (wr,wc) owns caption i = it*4+wc, images j = jt*4 + wr*2 + {0,1}.
    // C layout per frag: col = l15 (word), row = kgrp*4 + e (region).
    const int i_cap = it * 4 + wc;
    const int nw = s_l[i_cap];
    const float inv = 1.0f / (float)nw;
#pragma unroll
    for (int h = 0; h < 2; ++h) {       // image half: frags rf = h*3 .. h*3+2 (48 rows)
        float sum = 0.0f;
#pragma unroll
        for (int cf = 0; cf < 4; ++cf) {
            float m = acc[h * 3][cf][0];
#pragma unroll
            for (int rf = h * 3; rf < h * 3 + 3; ++rf)
#pragma unroll
                for (int e = 0; e < 4; ++e)
                    m = fmaxf(m, acc[rf][cf][e]);
            m = fmaxf(m, __shfl_xor(m, 16));
            m = fmaxf(m, __shfl_xor(m, 32));
            int wv = cf * 16 + l15;
            if (wv < nw) sum += m;
        }
        sum += __shfl_xor(sum, 1);
        sum += __shfl_xor(sum, 2);
        sum += __shfl_xor(sum, 4);
        sum += __shfl_xor(sum, 8);
        if (lane == 0) {
            int j_img = jt * 4 + wr * 2 + h;
            S[j_img * B_SZ + i_cap] = sum * inv;
        }
    }
}

// Contrastive loss over the 128x128 score matrix, single block
__global__ __launch_bounds__(256) void loss_kernel(
        const float* __restrict__ S, float* __restrict__ out) {
    __shared__ float diag[B_SZ];
    __shared__ float red[256];
    int t = threadIdx.x;
    if (t < B_SZ) diag[t] = S[t * (B_SZ + 1)];
    __syncthreads();
    float acc = 0.0f;
    for (int idx = t; idx < B_SZ * B_SZ; idx += 256) {
        int a = idx >> 7, b = idx & (B_SZ - 1);
        if (a != b) {
            float v = S[idx];
            acc += fmaxf(MARGIN + v - diag[a], 0.0f)
                 + fmaxf(MARGIN + v - diag[b], 0.0f);
        }
    }
    red[t] = acc;
    __syncthreads();
    for (int s = 128; s > 0; s >>= 1) {
        if (t < s) red[t] += red[t + s];
        __syncthreads();
    }
    if (t == 0) out[0] = red[0];
}

extern "C" void kernel_launch(void* const* d_in, const int* in_sizes, int n_in,
                              void* d_out, int out_size, void* d_ws, size_t ws_size,
                              hipStream_t stream) {
    const float* im  = (const float*)d_in[0];
    const float* s   = (const float*)d_in[1];
    const int*   s_l = (const int*)d_in[2];
    // d_in[3] (x) unused by the math

    const int n_im_pad = B_SZ * RP_SZ * D_SZ;   // 6,291,456
    const int n_s_pad  = B_SZ * WP_SZ * D_SZ;   // 8,388,608

    unsigned short* imb = (unsigned short*)d_ws;
    unsigned short* sb  = imb + n_im_pad;
    float* S = (float*)(sb + n_s_pad);          // 128*128 floats

    convert_pad_kernel<<<(n_im_pad / 4 + 255) / 256, 256, 0, stream>>>(
        im, imb, RP_SZ, R_SZ, n_im_pad / 4);
    convert_pad_kernel<<<(n_s_pad / 4 + 255) / 256, 256, 0, stream>>>(
        s, sb, WP_SZ, W_SZ, n_s_pad / 4);

    scores_kernel<<<1024, 512, 0, stream>>>(imb, sb, s_l, S);

    loss_kernel<<<1, 256, 0, stream>>>(S, (float*)d_out);
}

// Round 3
// 149.804 us; speedup vs baseline: 2.9242x; 1.0887x over previous
//
#include <hip/hip_runtime.h>
#include <hip/hip_bf16.h>
#include <stdint.h>

// Problem dims (fixed by reference setup_inputs)
#define B_SZ 128
#define R_SZ 36       // real regions per image
#define RP_SZ 48      // padded regions (dup row 35) -> multiple of 16
#define W_SZ 60       // real words per caption
#define WP_SZ 64      // padded words (dup word 59, masked in epilogue)
#define D_SZ 1024
#define MARGIN 0.2f

#define ATILE (192 * 64)   // bf16 elems per A K-tile
#define BTILE (256 * 64)   // bf16 elems per B K-tile

typedef __attribute__((ext_vector_type(8))) short short8;   // 8 bf16 (MFMA A/B frag)
typedef __attribute__((ext_vector_type(4))) float f32x4;    // MFMA C/D frag

typedef __attribute__((address_space(3))) unsigned int lds_u32;
typedef const __attribute__((address_space(1))) unsigned int glb_u32;

__device__ __forceinline__ void gload16(const unsigned short* g, unsigned short* l) {
    __builtin_amdgcn_global_load_lds((glb_u32*)g, (lds_u32*)l, 16, 0, 0);
}

__device__ __forceinline__ unsigned short f2bf(float f) {
    union { float f; uint32_t u; } x; x.f = f;
    uint32_t u = x.u;
    uint32_t r = (u + 0x7FFFu + ((u >> 16) & 1u)) >> 16;   // RNE bf16
    return (unsigned short)r;
}

// Fused fp32 -> bf16 convert + row-pad for BOTH tensors in one launch.
// im: [128][36][1024] -> imb [128][48][1024]; s: [128][60][1024] -> sb [128][64][1024]
__global__ __launch_bounds__(256) void convert_pad_kernel(
        const float* __restrict__ im, const float* __restrict__ s,
        unsigned short* __restrict__ imb, unsigned short* __restrict__ sb) {
    const int n4_im = B_SZ * RP_SZ * D_SZ / 4;
    const int n4_s  = B_SZ * WP_SZ * D_SZ / 4;
    int i = blockIdx.x * 256 + threadIdx.x;
    const float* src;
    unsigned short* dst;
    int srcIdx;
    if (i < n4_im) {
        int idx = i * 4;
        int d  = idx & (D_SZ - 1);
        int rj = idx >> 10;
        int r  = rj % RP_SZ;
        int j  = rj / RP_SZ;
        int rs = r < R_SZ ? r : R_SZ - 1;
        src = im; dst = imb + idx;
        srcIdx = ((j * R_SZ + rs) << 10) + d;
    } else {
        int i2 = i - n4_im;
        if (i2 >= n4_s) return;
        int idx = i2 * 4;
        int d  = idx & (D_SZ - 1);
        int rj = idx >> 10;
        int r  = rj & (WP_SZ - 1);
        int j  = rj >> 6;
        int rs = r < W_SZ ? r : W_SZ - 1;
        src = s; dst = sb + idx;
        srcIdx = ((j * W_SZ + rs) << 10) + d;
    }
    const float4 v = *reinterpret_cast<const float4*>(src + srcIdx);
    ushort4 o;
    o.x = f2bf(v.x); o.y = f2bf(v.y); o.z = f2bf(v.z); o.w = f2bf(v.w);
    *reinterpret_cast<ushort4*>(dst) = o;
}

// Fused GEMM + MISA epilogue, T3+T4+T5 schedule:
// Block tile BM=192 x BN=256, BK=64, 8 waves (2Mx4N), per-wave 96x64 (acc[6][4]).
// Double-buffered LDS (112 KB): prefetch tile kt+1 while computing kt; counted
// s_waitcnt vmcnt(7) keeps next tile's 7 loads in flight across raw s_barrier.
// XOR slot-swizzle (slot ^= row&7): linear global_load_lds dest + pre-swizzled
// global source + swizzled ds_read (round-2 verified, 0 bank conflicts).
__global__ __launch_bounds__(512, 2) void scores_kernel(
        const unsigned short* __restrict__ imb,   // [128][48][1024] bf16 (padded)
        const unsigned short* __restrict__ sb,    // [128][64][1024] bf16 (padded)
        const int* __restrict__ s_l,
        float* __restrict__ S)                    // [j][i]
{
    __shared__ unsigned short As[2 * ATILE];
    __shared__ unsigned short Bs[2 * BTILE];

    const int tid  = threadIdx.x;
    const int wid  = tid >> 6;        // 0..7
    const int lane = tid & 63;
    const int l15  = lane & 15;
    const int kgrp = lane >> 4;       // 0..3
    const int wr   = wid >> 2;        // 0..1 (M)
    const int wc   = wid & 3;         // 0..3 (N)

    // XCD-chunked swizzle over 1024 blocks (it-major chunks: B-panel per XCD L2)
    int bid = blockIdx.x;
    int swz = (bid & 7) * 128 + (bid >> 3);
    int jt = swz & 31;                // 0..31 (4 images each)
    int it = swz >> 5;                // 0..31 (4 captions each)

    // staging decomposition: 8 lanes per 128B row-segment, pre-swizzled source slot
    const int lrow = lane >> 3;                   // 0..7 == row&7 of the staged row
    const int slot = (lane & 7) ^ lrow;           // so LDS[row][s] = G[row][s^(row&7)]

    const unsigned short* gA[3];
    int aoff[3];
#pragma unroll
    for (int c = 0; c < 3; ++c) {
        int chunk = wid + c * 8;                  // 0..23
        int row = chunk * 8 + lrow;               // 0..191
        gA[c] = imb + (size_t)(jt * 192 + row) * D_SZ + slot * 8;
        aoff[c] = chunk * 512 + lane * 8;         // linear: base + lane*16B
    }
    const unsigned short* gB[4];
    int boff[4];
#pragma unroll
    for (int c = 0; c < 4; ++c) {
        int chunk = wid + c * 8;                  // 0..31
        int row = chunk * 8 + lrow;               // 0..255
        gB[c] = sb + (size_t)(it * 256 + row) * D_SZ + slot * 8;
        boff[c] = chunk * 512 + lane * 8;
    }

    f32x4 acc[6][4] = {};

    // prologue: stage tile 0 into buffer 0
#pragma unroll
    for (int c = 0; c < 3; ++c) gload16(gA[c], As + aoff[c]);
#pragma unroll
    for (int c = 0; c < 4; ++c) gload16(gB[c], Bs + boff[c]);

    // ds_read slot index (per lane, constant across iters except k2)
    const int rsw = l15 & 7;

    for (int kt = 0; kt < 16; ++kt) {
        const int cur = kt & 1;
        if (kt < 15) {
            const int nxt = cur ^ 1;
            const int ko = (kt + 1) * 64;
            unsigned short* Ad = As + nxt * ATILE;
            unsigned short* Bd = Bs + nxt * BTILE;
#pragma unroll
            for (int c = 0; c < 3; ++c) gload16(gA[c] + ko, Ad + aoff[c]);
#pragma unroll
            for (int c = 0; c < 4; ++c) gload16(gB[c] + ko, Bd + boff[c]);
            asm volatile("s_waitcnt vmcnt(7)" ::: "memory");  // tile kt landed; kt+1 in flight
        } else {
            asm volatile("s_waitcnt vmcnt(0)" ::: "memory");  // last tile: drain
        }
        __builtin_amdgcn_s_barrier();     // raw barrier: no vmcnt(0) auto-drain

        const unsigned short* Ac = As + cur * ATILE;
        const unsigned short* Bc = Bs + cur * BTILE;
        short8 a[2][6], b[2][4];
#pragma unroll
        for (int k2 = 0; k2 < 2; ++k2) {
#pragma unroll
            for (int rf = 0; rf < 6; ++rf) {
                int row = wr * 96 + rf * 16 + l15;
                int sl = (k2 * 4 + kgrp) ^ rsw;
                a[k2][rf] = *reinterpret_cast<const short8*>(Ac + row * 64 + sl * 8);
            }
#pragma unroll
            for (int cf = 0; cf < 4; ++cf) {
                int row = wc * 64 + cf * 16 + l15;
                int sl = (k2 * 4 + kgrp) ^ rsw;
                b[k2][cf] = *reinterpret_cast<const short8*>(Bc + row * 64 + sl * 8);
            }
        }
        __builtin_amdgcn_s_setprio(1);
#pragma unroll
        for (int k2 = 0; k2 < 2; ++k2)
#pragma unroll
            for (int rf = 0; rf < 6; ++rf)
#pragma unroll
                for (int cf = 0; cf < 4; ++cf)
                    acc[rf][cf] = __builtin_amdgcn_mfma_f32_16x16x32_bf16(
                        a[k2][rf], b[k2][cf], acc[rf][cf], 0, 0, 0);
        __builtin_amdgcn_s_setprio(0);
        asm volatile("s_waitcnt lgkmcnt(0)" ::: "memory");   // all reads of buf[cur] retired
        __builtin_amdgcn_s_barrier();     // next iter may overwrite buf[cur]
    }

    // Epilogue: wave (wr,wc) owns caption i = it*4+wc, images j = jt*4 + wr*2 + {0,1}.
    // C frag layout: col = l15 (word), row = kgrp*4 + e (region).
    const int i_cap = it * 4 + wc;
    const int nw = s_l[i_cap];
    const float inv = 1.0f / (float)nw;
#pragma unroll
    for (int h = 0; h < 2; ++h) {       // image half: frags rf = h*3 .. h*3+2 (48 rows)
        float sum = 0.0f;
#pragma unroll
        for (int cf = 0; cf < 4; ++cf) {
            float m = acc[h * 3][cf][0];
#pragma unroll
            for (int rf = h * 3; rf < h * 3 + 3; ++rf)
#pragma unroll
                for (int e = 0; e < 4; ++e)
                    m = fmaxf(m, acc[rf][cf][e]);
            m = fmaxf(m, __shfl_xor(m, 16));
            m = fmaxf(m, __shfl_xor(m, 32));
            int wv = cf * 16 + l15;
            if (wv < nw) sum += m;
        }
        sum += __shfl_xor(sum, 1);
        sum += __shfl_xor(sum, 2);
        sum += __shfl_xor(sum, 4);
        sum += __shfl_xor(sum, 8);
        if (lane == 0) {
            int j_img = jt * 4 + wr * 2 + h;
            S[j_img * B_SZ + i_cap] = sum * inv;
        }
    }
}

// Contrastive loss over the 128x128 score matrix, single block
__global__ __launch_bounds__(256) void loss_kernel(
        const float* __restrict__ S, float* __restrict__ out) {
    __shared__ float diag[B_SZ];
    __shared__ float red[256];
    int t = threadIdx.x;
    if (t < B_SZ) diag[t] = S[t * (B_SZ + 1)];
    __syncthreads();
    float acc = 0.0f;
    for (int idx = t; idx < B_SZ * B_SZ; idx += 256) {
        int a = idx >> 7, b = idx & (B_SZ - 1);
        if (a != b) {
            float v = S[idx];
            acc += fmaxf(MARGIN + v - diag[a], 0.0f)
                 + fmaxf(MARGIN + v - diag[b], 0.0f);
        }
    }
    red[t] = acc;
    __syncthreads();
    for (int s = 128; s > 0; s >>= 1) {
        if (t < s) red[t] += red[t + s];
        __syncthreads();
    }
    if (t == 0) out[0] = red[0];
}

extern "C" void kernel_launch(void* const* d_in, const int* in_sizes, int n_in,
                              void* d_out, int out_size, void* d_ws, size_t ws_size,
                              hipStream_t stream) {
    const float* im  = (const float*)d_in[0];
    const float* s   = (const float*)d_in[1];
    const int*   s_l = (const int*)d_in[2];
    // d_in[3] (x) unused by the math

    const int n_im_pad = B_SZ * RP_SZ * D_SZ;   // 6,291,456
    const int n_s_pad  = B_SZ * WP_SZ * D_SZ;   // 8,388,608

    unsigned short* imb = (unsigned short*)d_ws;
    unsigned short* sb  = imb + n_im_pad;
    float* S = (float*)(sb + n_s_pad);          // 128*128 floats

    const int n4_total = (n_im_pad + n_s_pad) / 4;
    convert_pad_kernel<<<(n4_total + 255) / 256, 256, 0, stream>>>(im, s, imb, sb);

    scores_kernel<<<1024, 512, 0, stream>>>(imb, sb, s_l, S);

    loss_kernel<<<1, 256, 0, stream>>>(S, (float*)d_out);
}

// Round 4
// 137.537 us; speedup vs baseline: 3.1850x; 1.0892x over previous
//
#include <hip/hip_runtime.h>
#include <hip/hip_bf16.h>
#include <stdint.h>

// Problem dims (fixed by reference setup_inputs)
#define B_SZ 128
#define R_SZ 36       // real regions per image
#define RP_SZ 48      // padded regions (dup row 35) -> multiple of 16
#define W_SZ 60       // real words per caption
#define WP_SZ 64      // padded words (dup word 59, masked in epilogue)
#define D_SZ 1024
#define MARGIN 0.2f

#define ATILE (192 * 64)   // bf16 elems per A K-tile
#define BTILE (256 * 64)   // bf16 elems per B K-tile

typedef __attribute__((ext_vector_type(8))) short short8;   // 8 bf16 (MFMA A/B frag)
typedef __attribute__((ext_vector_type(4))) float f32x4;    // MFMA C/D frag

typedef __attribute__((address_space(3))) unsigned int lds_u32;
typedef const __attribute__((address_space(1))) unsigned int glb_u32;

__device__ __forceinline__ void gload16(const unsigned short* g, unsigned short* l) {
    __builtin_amdgcn_global_load_lds((glb_u32*)g, (lds_u32*)l, 16, 0, 0);
}

__device__ __forceinline__ unsigned short f2bf(float f) {
    union { float f; uint32_t u; } x; x.f = f;
    uint32_t u = x.u;
    uint32_t r = (u + 0x7FFFu + ((u >> 16) & 1u)) >> 16;   // RNE bf16
    return (unsigned short)r;
}

// Fused fp32 -> bf16 convert + row-pad for BOTH tensors in one launch.
// im: [128][36][1024] -> imb [128][48][1024]; s: [128][60][1024] -> sb [128][64][1024]
__global__ __launch_bounds__(256) void convert_pad_kernel(
        const float* __restrict__ im, const float* __restrict__ s,
        unsigned short* __restrict__ imb, unsigned short* __restrict__ sb) {
    const int n4_im = B_SZ * RP_SZ * D_SZ / 4;
    const int n4_s  = B_SZ * WP_SZ * D_SZ / 4;
    int i = blockIdx.x * 256 + threadIdx.x;
    const float* src;
    unsigned short* dst;
    int srcIdx;
    if (i < n4_im) {
        int idx = i * 4;
        int d  = idx & (D_SZ - 1);
        int rj = idx >> 10;
        int r  = rj % RP_SZ;
        int j  = rj / RP_SZ;
        int rs = r < R_SZ ? r : R_SZ - 1;
        src = im; dst = imb + idx;
        srcIdx = ((j * R_SZ + rs) << 10) + d;
    } else {
        int i2 = i - n4_im;
        if (i2 >= n4_s) return;
        int idx = i2 * 4;
        int d  = idx & (D_SZ - 1);
        int rj = idx >> 10;
        int r  = rj & (WP_SZ - 1);
        int j  = rj >> 6;
        int rs = r < W_SZ ? r : W_SZ - 1;
        src = s; dst = sb + idx;
        srcIdx = ((j * W_SZ + rs) << 10) + d;
    }
    const float4 v = *reinterpret_cast<const float4*>(src + srcIdx);
    ushort4 o;
    o.x = f2bf(v.x); o.y = f2bf(v.y); o.z = f2bf(v.z); o.w = f2bf(v.w);
    *reinterpret_cast<ushort4*>(dst) = o;
}

// Fused GEMM + MISA epilogue, phased T3+T4+T5 schedule:
// Block tile BM=192 x BN=256, BK=64, 8 waves (2Mx4N), per-wave 96x64 (acc[6][4]).
// Each K-tile = 2 phases (k2 slices). Per phase: 10 ds_read_b128 + stage issue
// -> s_barrier -> lgkmcnt(0) -> setprio(1) -> 24 MFMA -> setprio(0) -> s_barrier.
// Stage of tile kt+1 (7 global_load_lds) issued in phase 0; counted vmcnt(0)
// sits after phase 1's MFMA cluster (loads fly under ~1500+ cyc of compute).
// Double-buffered LDS 112 KB; XOR slot-swizzle as validated in rounds 2-3.
__global__ __launch_bounds__(512, 2) void scores_kernel(
        const unsigned short* __restrict__ imb,   // [128][48][1024] bf16 (padded)
        const unsigned short* __restrict__ sb,    // [128][64][1024] bf16 (padded)
        const int* __restrict__ s_l,
        float* __restrict__ S)                    // [j][i]
{
    __shared__ unsigned short As[2 * ATILE];
    __shared__ unsigned short Bs[2 * BTILE];

    const int tid  = threadIdx.x;
    const int wid  = tid >> 6;        // 0..7
    const int lane = tid & 63;
    const int l15  = lane & 15;
    const int kgrp = lane >> 4;       // 0..3
    const int wr   = wid >> 2;        // 0..1 (M)
    const int wc   = wid & 3;         // 0..3 (N)

    // XCD-chunked swizzle over 1024 blocks (it-major chunks: B-panel per XCD L2)
    int bid = blockIdx.x;
    int swz = (bid & 7) * 128 + (bid >> 3);
    int jt = swz & 31;                // 0..31 (4 images each)
    int it = swz >> 5;                // 0..31 (4 captions each)

    // staging decomposition: 8 lanes per 128B row-segment, pre-swizzled source slot
    const int lrow = lane >> 3;                   // 0..7 == row&7 of the staged row
    const int slot = (lane & 7) ^ lrow;           // so LDS[row][s] = G[row][s^(row&7)]

    const unsigned short* gA[3];
    int aoff[3];
#pragma unroll
    for (int c = 0; c < 3; ++c) {
        int chunk = wid + c * 8;                  // 0..23
        int row = chunk * 8 + lrow;               // 0..191
        gA[c] = imb + (size_t)(jt * 192 + row) * D_SZ + slot * 8;
        aoff[c] = chunk * 512 + lane * 8;         // linear: base + lane*16B
    }
    const unsigned short* gB[4];
    int boff[4];
#pragma unroll
    for (int c = 0; c < 4; ++c) {
        int chunk = wid + c * 8;                  // 0..31
        int row = chunk * 8 + lrow;               // 0..255
        gB[c] = sb + (size_t)(it * 256 + row) * D_SZ + slot * 8;
        boff[c] = chunk * 512 + lane * 8;
    }

    // LDS read addressing (elements): addr = row*64 + slot*8, slot = (k2*4+kgrp)^rsw
    // k2=1 address = k2=0 address ^ 32 (bit 5 of the element offset)
    const int rsw = l15 & 7;
    const int k0off = (kgrp ^ rsw) * 8;
    int abase[6];
#pragma unroll
    for (int rf = 0; rf < 6; ++rf)
        abase[rf] = (wr * 96 + rf * 16 + l15) * 64 + k0off;
    int bbase[4];
#pragma unroll
    for (int cf = 0; cf < 4; ++cf)
        bbase[cf] = (wc * 64 + cf * 16 + l15) * 64 + k0off;

    f32x4 acc[6][4] = {};

    // prologue: stage tile 0 into buffer 0, drain, sync
#pragma unroll
    for (int c = 0; c < 3; ++c) gload16(gA[c], As + aoff[c]);
#pragma unroll
    for (int c = 0; c < 4; ++c) gload16(gB[c], Bs + boff[c]);
    asm volatile("s_waitcnt vmcnt(0)" ::: "memory");
    __builtin_amdgcn_s_barrier();

    for (int kt = 0; kt < 16; ++kt) {
        const int cur = kt & 1;
        const unsigned short* Ac = As + cur * ATILE;
        const unsigned short* Bc = Bs + cur * BTILE;
        unsigned short* Ad = As + (cur ^ 1) * ATILE;
        unsigned short* Bd = Bs + (cur ^ 1) * BTILE;
        const int ko = (kt + 1) * 64;
        const bool pf = (kt < 15);

        short8 a[6], b[4];

        // ===== phase 0 (k2 = 0) =====
#pragma unroll
        for (int rf = 0; rf < 6; ++rf)
            a[rf] = *reinterpret_cast<const short8*>(Ac + abase[rf]);
#pragma unroll
        for (int cf = 0; cf < 4; ++cf)
            b[cf] = *reinterpret_cast<const short8*>(Bc + bbase[cf]);
        if (pf) {   // stage ALL of tile kt+1 here: max flight time before vmcnt
#pragma unroll
            for (int c = 0; c < 4; ++c) gload16(gB[c] + ko, Bd + boff[c]);
#pragma unroll
            for (int c = 0; c < 3; ++c) gload16(gA[c] + ko, Ad + aoff[c]);
        }
        __builtin_amdgcn_s_barrier();
        asm volatile("s_waitcnt lgkmcnt(0)" ::: "memory");
        __builtin_amdgcn_s_setprio(1);
#pragma unroll
        for (int rf = 0; rf < 6; ++rf)
#pragma unroll
            for (int cf = 0; cf < 4; ++cf)
                acc[rf][cf] = __builtin_amdgcn_mfma_f32_16x16x32_bf16(
                    a[rf], b[cf], acc[rf][cf], 0, 0, 0);
        __builtin_amdgcn_s_setprio(0);
        __builtin_amdgcn_s_barrier();

        // ===== phase 1 (k2 = 1) =====
#pragma unroll
        for (int rf = 0; rf < 6; ++rf)
            a[rf] = *reinterpret_cast<const short8*>(Ac + (abase[rf] ^ 32));
#pragma unroll
        for (int cf = 0; cf < 4; ++cf)
            b[cf] = *reinterpret_cast<const short8*>(Bc + (bbase[cf] ^ 32));
        __builtin_amdgcn_s_barrier();
        asm volatile("s_waitcnt lgkmcnt(0)" ::: "memory");
        __builtin_amdgcn_s_setprio(1);
#pragma unroll
        for (int rf = 0; rf < 6; ++rf)
#pragma unroll
            for (int cf = 0; cf < 4; ++cf)
                acc[rf][cf] = __builtin_amdgcn_mfma_f32_16x16x32_bf16(
                    a[rf], b[cf], acc[rf][cf], 0, 0, 0);
        __builtin_amdgcn_s_setprio(0);
        if (pf) asm volatile("s_waitcnt vmcnt(0)" ::: "memory");  // tile kt+1 landed
        __builtin_amdgcn_s_barrier();
    }

    // Epilogue: wave (wr,wc) owns caption i = it*4+wc, images j = jt*4 + wr*2 + {0,1}.
    // C frag layout: col = l15 (word), row = kgrp*4 + e (region).
    const int i_cap = it * 4 + wc;
    const int nw = s_l[i_cap];
    const float inv = 1.0f / (float)nw;
#pragma unroll
    for (int h = 0; h < 2; ++h) {       // image half: frags rf = h*3 .. h*3+2 (48 rows)
        float sum = 0.0f;
#pragma unroll
        for (int cf = 0; cf < 4; ++cf) {
            float m = acc[h * 3][cf][0];
#pragma unroll
            for (int rf = h * 3; rf < h * 3 + 3; ++rf)
#pragma unroll
                for (int e = 0; e < 4; ++e)
                    m = fmaxf(m, acc[rf][cf][e]);
            m = fmaxf(m, __shfl_xor(m, 16));
            m = fmaxf(m, __shfl_xor(m, 32));
            int wv = cf * 16 + l15;
            if (wv < nw) sum += m;
        }
        sum += __shfl_xor(sum, 1);
        sum += __shfl_xor(sum, 2);
        sum += __shfl_xor(sum, 4);
        sum += __shfl_xor(sum, 8);
        if (lane == 0) {
            int j_img = jt * 4 + wr * 2 + h;
            S[j_img * B_SZ + i_cap] = sum * inv;
        }
    }
}

// Contrastive loss over the 128x128 score matrix, single block
__global__ __launch_bounds__(256) void loss_kernel(
        const float* __restrict__ S, float* __restrict__ out) {
    __shared__ float diag[B_SZ];
    __shared__ float red[256];
    int t = threadIdx.x;
    if (t < B_SZ) diag[t] = S[t * (B_SZ + 1)];
    __syncthreads();
    float acc = 0.0f;
    for (int idx = t; idx < B_SZ * B_SZ; idx += 256) {
        int a = idx >> 7, b = idx & (B_SZ - 1);
        if (a != b) {
            float v = S[idx];
            acc += fmaxf(MARGIN + v - diag[a], 0.0f)
                 + fmaxf(MARGIN + v - diag[b], 0.0f);
        }
    }
    red[t] = acc;
    __syncthreads();
    for (int s = 128; s > 0; s >>= 1) {
        if (t < s) red[t] += red[t + s];
        __syncthreads();
    }
    if (t == 0) out[0] = red[0];
}

extern "C" void kernel_launch(void* const* d_in, const int* in_sizes, int n_in,
                              void* d_out, int out_size, void* d_ws, size_t ws_size,
                              hipStream_t stream) {
    const float* im  = (const float*)d_in[0];
    const float* s   = (const float*)d_in[1];
    const int*   s_l = (const int*)d_in[2];
    // d_in[3] (x) unused by the math

    const int n_im_pad = B_SZ * RP_SZ * D_SZ;   // 6,291,456
    const int n_s_pad  = B_SZ * WP_SZ * D_SZ;   // 8,388,608

    unsigned short* imb = (unsigned short*)d_ws;
    unsigned short* sb  = imb + n_im_pad;
    float* S = (float*)(sb + n_s_pad);          // 128*128 floats

    const int n4_total = (n_im_pad + n_s_pad) / 4;
    convert_pad_kernel<<<(n4_total + 255) / 256, 256, 0, stream>>>(im, s, imb, sb);

    scores_kernel<<<1024, 512, 0, stream>>>(imb, sb, s_l, S);

    loss_kernel<<<1, 256, 0, stream>>>(S, (float*)d_out);
}